// Round 17
// baseline (102.840 us; speedup 1.0000x reference)
//
#include <hip/hip_runtime.h>

typedef short bf16x8 __attribute__((ext_vector_type(8)));
typedef float f32x4 __attribute__((ext_vector_type(4)));
typedef float f32x16 __attribute__((ext_vector_type(16)));
typedef unsigned u32x4v __attribute__((ext_vector_type(4)));

#define T_SEQ 4096
#define CDIM  1024
#define HD    64
#define NROWS 16384  // B*T

__device__ inline float exp2fast(float x) {
  return __builtin_amdgcn_exp2f(x);   // v_exp_f32: D = 2^S0
}

__device__ inline unsigned short f2bf(float f) {
  unsigned u = __builtin_bit_cast(unsigned, f);
  u = (u + 0x7fffu + ((u >> 16) & 1u)) >> 16;
  return (unsigned short)u;
}
__device__ inline unsigned cvt_pk_bf16(float lo, float hi) {
  unsigned r;
  asm("v_cvt_pk_bf16_f32 %0, %1, %2" : "=v"(r) : "v"(lo), "v"(hi));
  return r;
}
__device__ inline float bf2f(unsigned short u) {
  unsigned v = (unsigned)u << 16;
  return __builtin_bit_cast(float, v);
}

// ---------------- W prep: Wt[n][k] bf16, n<64 = Wk col n, n>=64 = Wv col ----------------
__global__ __launch_bounds__(256) void prep_w(
    const float* __restrict__ Wk, const float* __restrict__ Wv,
    unsigned short* __restrict__ Wt) {
  int n = blockIdx.x;
  const float* W = (n < 64) ? Wk : Wv;
  int col = n & 63;
  for (int k = threadIdx.x; k < CDIM; k += 256)
    Wt[(size_t)n * CDIM + k] = f2bf(W[(size_t)k * HD + col]);
}

// ---------------- projection GEMM: [K|V] = x @ Wt^T, bf16 MFMA ----------------
// (byte-identical to round 14/15/16)
__global__ __launch_bounds__(256) void proj_mfma(
    const float* __restrict__ x, const unsigned short* __restrict__ Wt,
    unsigned short* __restrict__ Kb, unsigned short* __restrict__ Vb) {
  __shared__ __align__(16) unsigned char xsb[16384];
  __shared__ __align__(16) unsigned char wsb[32768];
  const int tid = threadIdx.x;
  const int lane = tid & 63, wave = tid >> 6;
  const int wm = wave & 1, wn = wave >> 1;
  const int lg = lane >> 4, lc = lane & 15;
  const int row0 = blockIdx.x * 64;

  float4 xreg[8];
  uint4 wreg[8];
  auto load_tiles = [&](int kk) {
    #pragma unroll
    for (int p = 0; p < 8; ++p) {
      int idx = tid + 256 * p, r = idx >> 5, c4 = idx & 31;
      xreg[p] = *(const float4*)&x[(size_t)(row0 + r) * CDIM + kk + c4 * 4];
    }
    #pragma unroll
    for (int p = 0; p < 8; ++p) {
      int idx = tid + 256 * p, r = idx >> 4, c8 = idx & 15;
      wreg[p] = *(const uint4*)&Wt[(size_t)r * CDIM + kk + c8 * 8];
    }
  };
  auto write_tiles = [&]() {
    #pragma unroll
    for (int p = 0; p < 8; ++p) {
      int idx = tid + 256 * p, r = idx >> 5, c4 = idx & 31;
      uint2 v;
      v.x = cvt_pk_bf16(xreg[p].x, xreg[p].y);
      v.y = cvt_pk_bf16(xreg[p].z, xreg[p].w);
      int byt = (r * 256 + c4 * 8) ^ ((r & 7) << 4);
      *(uint2*)(xsb + byt) = v;
    }
    #pragma unroll
    for (int p = 0; p < 8; ++p) {
      int idx = tid + 256 * p, r = idx >> 4, c8 = idx & 15;
      int byt = (r * 256 + c8 * 16) ^ ((r & 7) << 4);
      *(uint4*)(wsb + byt) = wreg[p];
    }
  };

  f32x4 acc[2][4];
  #pragma unroll
  for (int mf = 0; mf < 2; ++mf)
    #pragma unroll
    for (int nf = 0; nf < 4; ++nf) acc[mf][nf] = (f32x4){0.f, 0.f, 0.f, 0.f};

  load_tiles(0);
  for (int kk = 0; kk < CDIM; kk += 128) {
    __syncthreads();
    write_tiles();
    __syncthreads();
    if (kk + 128 < CDIM) load_tiles(kk + 128);
    #pragma unroll
    for (int dd = 0; dd < 4; ++dd) {
      bf16x8 a[2], bfr[4];
      #pragma unroll
      for (int mf = 0; mf < 2; ++mf) {
        int r = wm * 32 + mf * 16 + lc;
        int sw = (r & 7) << 4;
        a[mf] = *(const bf16x8*)(xsb + ((r * 256 + dd * 64 + lg * 16) ^ sw));
      }
      #pragma unroll
      for (int nf = 0; nf < 4; ++nf) {
        int r = wn * 64 + nf * 16 + lc;
        int sw = (r & 7) << 4;
        bfr[nf] = *(const bf16x8*)(wsb + ((r * 256 + dd * 64 + lg * 16) ^ sw));
      }
      __builtin_amdgcn_s_setprio(1);
      #pragma unroll
      for (int mf = 0; mf < 2; ++mf)
        #pragma unroll
        for (int nf = 0; nf < 4; ++nf)
          acc[mf][nf] = __builtin_amdgcn_mfma_f32_16x16x32_bf16(a[mf], bfr[nf], acc[mf][nf], 0, 0, 0);
      __builtin_amdgcn_s_setprio(0);
    }
  }

  unsigned short* Ob = (wn == 0) ? Kb : Vb;
  #pragma unroll
  for (int mf = 0; mf < 2; ++mf)
    #pragma unroll
    for (int r = 0; r < 4; ++r) {
      int rg = row0 + wm * 32 + mf * 16 + lg * 4 + r;
      #pragma unroll
      for (int nf = 0; nf < 4; ++nf)
        Ob[(size_t)rg * HD + nf * 16 + lc] = f2bf(acc[nf == 0 ? mf : mf][nf][r]);
    }
}

// ---------------- split-K flash attention, swapped QK^T, 32x32 MFMA ----------------
// Each wave owns 64 q-rows (tiles A: q0g+lq, B: q0g+32+lq) sharing the K/V stream.
// Block = 4 waves x 64 q = 256 q-rows; chunk = 256 keys; nit = 4 uniformly. 544 blocks.
__global__ __launch_bounds__(256) void attn_part(
    const unsigned short* __restrict__ Kb, const unsigned short* __restrict__ Vb,
    unsigned short* __restrict__ Opart, float* __restrict__ Ml) {
  __shared__ __align__(16) unsigned char lds[32768];  // 2 bufs x (K 8KB + V^T 8KB)

  const int tid = threadIdx.x;
  const int lane = tid & 63;
  const int wq = tid >> 6;
  const int hi = lane >> 5;
  const int lq = lane & 31;

  const int b = blockIdx.x & 3;
  int qp = 0, c = 0;
  {
    int u = blockIdx.x >> 2, acc = 0;
    for (int q = 15; q >= 0; --q) {      // heavy (qp=15) chunks first
      int nch = q + 1;                   // (qp+1)*256 keys / 256-key chunks
      if (u < acc + nch) { qp = q; c = u - acc; break; }
      acc += nch;
    }
  }
  const int kstart = c * 256;            // kend = kstart+256 always; nit = 4
  const int q0g = qp * 256 + wq * 64;
  const int qgA = q0g + lq;
  const int qgB = q0g + 32 + lq;
  const size_t base = (size_t)b * T_SEQ;
  const float SCALE2 = 0.18033688011112042f;     // 0.125 * log2(e)

  // Q B-fragments, pre-scaled by SCALE2: tiles A (rows q0g+lq) and B (rows q0g+32+lq)
  bf16x8 qfA[4], qfB[4];
  {
    const unsigned short* qpA = &Kb[(base + q0g + lq) * HD];
    const unsigned short* qpB = &Kb[(base + q0g + 32 + lq) * HD];
    #pragma unroll
    for (int dd = 0; dd < 4; ++dd) {
      bf16x8 tA = *(const bf16x8*)&qpA[dd * 16 + hi * 8];
      bf16x8 tB = *(const bf16x8*)&qpB[dd * 16 + hi * 8];
      const unsigned short* tsA = (const unsigned short*)&tA;
      const unsigned short* tsB = (const unsigned short*)&tB;
      unsigned owA[4], owB[4];
      #pragma unroll
      for (int w = 0; w < 4; ++w) {
        owA[w] = cvt_pk_bf16(bf2f(tsA[2 * w]) * SCALE2, bf2f(tsA[2 * w + 1]) * SCALE2);
        owB[w] = cvt_pk_bf16(bf2f(tsB[2 * w]) * SCALE2, bf2f(tsB[2 * w + 1]) * SCALE2);
      }
      u32x4v ovA = {owA[0], owA[1], owA[2], owA[3]};
      u32x4v ovB = {owB[0], owB[1], owB[2], owB[3]};
      qfA[dd] = __builtin_bit_cast(bf16x8, ovA);
      qfB[dd] = __builtin_bit_cast(bf16x8, ovB);
    }
  }

  f32x16 oA0, oA1, oB0, oB1;
  #pragma unroll
  for (int r = 0; r < 16; ++r) { oA0[r] = 0.f; oA1[r] = 0.f; oB0[r] = 0.f; oB1[r] = 0.f; }
  float mA = -1e30f, lA = 0.f, mB = -1e30f, lB = 0.f;   // log2 domain

  uint4 kreg[2], vreg0, vreg1;
  auto load_kv = [&](int jj) {
    const size_t kv0 = (base + kstart + (size_t)jj * 64) * HD;
    #pragma unroll
    for (int p = 0; p < 2; ++p) {
      int idx = tid + 256 * p, r = idx >> 3, c8 = idx & 7;
      kreg[p] = *(const uint4*)&Kb[kv0 + (size_t)r * HD + c8 * 8];
    }
    int key0 = (tid & 31) * 2, d0 = (tid >> 5) * 8;
    vreg0 = *(const uint4*)&Vb[kv0 + (size_t)key0 * HD + d0];
    vreg1 = *(const uint4*)&Vb[kv0 + (size_t)(key0 + 1) * HD + d0];
  };
  auto write_kv = [&](int buf) {
    unsigned char* kb = lds + buf * 16384;
    unsigned char* vb = kb + 8192;
    #pragma unroll
    for (int p = 0; p < 2; ++p) {
      int idx = tid + 256 * p, r = idx >> 3, c8 = idx & 7;
      int byt = (r * 128 + c8 * 16) ^ ((r & 7) << 4);
      *(uint4*)(kb + byt) = kreg[p];
    }
    int key0 = (tid & 31) * 2, d0 = (tid >> 5) * 8;
    const unsigned short* pa = (const unsigned short*)&vreg0;
    const unsigned short* pb = (const unsigned short*)&vreg1;
    #pragma unroll
    for (int j = 0; j < 8; ++j) {
      unsigned val = (unsigned)pa[j] | ((unsigned)pb[j] << 16);
      int d = d0 + j;
      int byt = (d * 128 + key0 * 2) ^ ((d & 7) << 4);
      *(unsigned*)(vb + byt) = val;
    }
  };

  auto max16 = [&](const f32x16& s) -> float {
    return fmaxf(
        fmaxf(fmaxf(fmaxf(s[0], s[1]), fmaxf(s[2], s[3])),
              fmaxf(fmaxf(s[4], s[5]), fmaxf(s[6], s[7]))),
        fmaxf(fmaxf(fmaxf(s[8], s[9]), fmaxf(s[10], s[11])),
              fmaxf(fmaxf(s[12], s[13]), fmaxf(s[14], s[15]))));
  };
  auto pack2 = [&](const f32x16& s, bf16x8& p1, bf16x8& p2) {
    unsigned pk[8];
    #pragma unroll
    for (int i = 0; i < 8; ++i) pk[i] = cvt_pk_bf16(s[2 * i], s[2 * i + 1]);
    unsigned wA_[4], wB_[4];
    #pragma unroll
    for (int i = 0; i < 2; ++i) {
      unsigned a0 = pk[i], b0 = pk[2 + i];
      unsigned sa = (unsigned)__shfl_xor((int)a0, 32);
      unsigned sb = (unsigned)__shfl_xor((int)b0, 32);
      wA_[i] = hi ? sb : a0;
      wA_[2 + i] = hi ? b0 : sa;
      unsigned c0 = pk[4 + i], d0v = pk[6 + i];
      unsigned sc = (unsigned)__shfl_xor((int)c0, 32);
      unsigned sd = (unsigned)__shfl_xor((int)d0v, 32);
      wB_[i] = hi ? sd : c0;
      wB_[2 + i] = hi ? d0v : sc;
    }
    u32x4v t1v = {wA_[0], wA_[1], wA_[2], wA_[3]};
    u32x4v t2v = {wB_[0], wB_[1], wB_[2], wB_[3]};
    p1 = __builtin_bit_cast(bf16x8, t1v);
    p2 = __builtin_bit_cast(bf16x8, t2v);
  };
  // softmax + pack + PV for one q-tile
  auto smpv = [&](f32x16& s, float& m, float& l, f32x16& o0, f32x16& o1,
                  bool domask, int kbase_s, int qg_t, int buf, int ksub) {
    if (domask) {
      #pragma unroll
      for (int r = 0; r < 16; ++r) {
        int key = kbase_s + (r & 3) + 8 * (r >> 2) + 4 * hi;
        if (key > qg_t) s[r] = -1e38f;
      }
    }
    float mx = max16(s);
    mx = fmaxf(mx, __shfl_xor(mx, 32));
    if (!__all(mx <= m + 11.5f)) {
      float mn = fmaxf(m, mx);
      float al = exp2fast(m - mn);
      l *= al;
      #pragma unroll
      for (int r = 0; r < 16; ++r) { o0[r] *= al; o1[r] *= al; }
      m = mn;
    }
    float ps = 0.f;
    #pragma unroll
    for (int r = 0; r < 16; ++r) {
      float p = exp2fast(s[r] - m);
      ps += p;
      s[r] = p;
    }
    l += ps + __shfl_xor(ps, 32);
    bf16x8 p1, p2;
    pack2(s, p1, p2);
    const unsigned char* vb = lds + buf * 16384 + 8192;
    const int cb = ksub * 64;
    __builtin_amdgcn_s_setprio(1);
    {
      int drow = lq;
      int swz = (drow & 7) << 4;
      bf16x8 v0 = *(const bf16x8*)(vb + ((drow * 128 + cb + hi * 16) ^ swz));
      bf16x8 v1 = *(const bf16x8*)(vb + ((drow * 128 + cb + 32 + hi * 16) ^ swz));
      o0 = __builtin_amdgcn_mfma_f32_32x32x16_bf16(v0, p1, o0, 0, 0, 0);
      o0 = __builtin_amdgcn_mfma_f32_32x32x16_bf16(v1, p2, o0, 0, 0, 0);
    }
    {
      int drow = 32 + lq;
      int swz = (drow & 7) << 4;
      bf16x8 v0 = *(const bf16x8*)(vb + ((drow * 128 + cb + hi * 16) ^ swz));
      bf16x8 v1 = *(const bf16x8*)(vb + ((drow * 128 + cb + 32 + hi * 16) ^ swz));
      o1 = __builtin_amdgcn_mfma_f32_32x32x16_bf16(v0, p1, o1, 0, 0, 0);
      o1 = __builtin_amdgcn_mfma_f32_32x32x16_bf16(v1, p2, o1, 0, 0, 0);
    }
    __builtin_amdgcn_s_setprio(0);
  };

  load_kv(0);
  write_kv(0);
  for (int jj = 0; jj < 4; ++jj) {
    const int cur = jj & 1;
    __syncthreads();                     // buf[cur] staged
    if (jj + 1 < 4) load_kv(jj + 1);     // in flight during compute
    const int kb0 = kstart + jj * 64;

    #pragma unroll
    for (int ksub = 0; ksub < 2; ++ksub) {
      const int kbase_s = kb0 + ksub * 32;
      if (kbase_s > q0g + 32) continue;  // beyond both tiles' diagonal
      const unsigned char* kb = lds + cur * 16384;
      const int krow = ksub * 32 + lq;
      const int ksw = (krow & 7) << 4;
      bf16x8 kf[4];
      #pragma unroll
      for (int dd = 0; dd < 4; ++dd)
        kf[dd] = *(const bf16x8*)(kb + ((krow * 128 + dd * 32 + hi * 16) ^ ksw));
      const bool doA = kbase_s <= q0g;
      f32x16 sA, sB;
      #pragma unroll
      for (int r = 0; r < 16; ++r) { sA[r] = 0.f; sB[r] = 0.f; }
      __builtin_amdgcn_s_setprio(1);
      #pragma unroll
      for (int dd = 0; dd < 4; ++dd) {
        sB = __builtin_amdgcn_mfma_f32_32x32x16_bf16(kf[dd], qfB[dd], sB, 0, 0, 0);
        if (doA) sA = __builtin_amdgcn_mfma_f32_32x32x16_bf16(kf[dd], qfA[dd], sA, 0, 0, 0);
      }
      __builtin_amdgcn_s_setprio(0);
      if (doA) smpv(sA, mA, lA, oA0, oA1, kbase_s == q0g, kbase_s, qgA, cur, ksub);
      smpv(sB, mB, lB, oB0, oB1, kbase_s == q0g + 32, kbase_s, qgB, cur, ksub);
    }

    if (jj + 1 < 4) write_kv(cur ^ 1);   // vmcnt wait lands post-compute
  }

  // ---- write normalized bf16 partials [256 q][64 d] + (m2, l) ----
  unsigned short* op = Opart + (size_t)blockIdx.x * 16384;
  float* mlp = Ml + (size_t)blockIdx.x * 512;
  const float invA = 1.0f / lA;
  const float invB = 1.0f / lB;
  const int rowA = wq * 64 + lq;
  const int rowB = wq * 64 + 32 + lq;
  #pragma unroll
  for (int g = 0; g < 4; ++g) {
    int d0 = 8 * g + 4 * hi;
    uint2 wa0, wa1, wb0, wb1;
    wa0.x = cvt_pk_bf16(oA0[4 * g] * invA, oA0[4 * g + 1] * invA);
    wa0.y = cvt_pk_bf16(oA0[4 * g + 2] * invA, oA0[4 * g + 3] * invA);
    wa1.x = cvt_pk_bf16(oA1[4 * g] * invA, oA1[4 * g + 1] * invA);
    wa1.y = cvt_pk_bf16(oA1[4 * g + 2] * invA, oA1[4 * g + 3] * invA);
    wb0.x = cvt_pk_bf16(oB0[4 * g] * invB, oB0[4 * g + 1] * invB);
    wb0.y = cvt_pk_bf16(oB0[4 * g + 2] * invB, oB0[4 * g + 3] * invB);
    wb1.x = cvt_pk_bf16(oB1[4 * g] * invB, oB1[4 * g + 1] * invB);
    wb1.y = cvt_pk_bf16(oB1[4 * g + 2] * invB, oB1[4 * g + 3] * invB);
    *(uint2*)&op[rowA * 64 + d0] = wa0;
    *(uint2*)&op[rowA * 64 + d0 + 32] = wa1;
    *(uint2*)&op[rowB * 64 + d0] = wb0;
    *(uint2*)&op[rowB * 64 + d0 + 32] = wb1;
  }
  if (hi == 0) {
    mlp[rowA * 2] = mA;
    mlp[rowA * 2 + 1] = lA;
    mlp[rowB * 2] = mB;
    mlp[rowB * 2 + 1] = lB;
  }
}

// ---------------- phase 2: merge chunk partials (8 d per thread, uint4 loads) ----------------
__global__ __launch_bounds__(256) void attn_merge(
    const unsigned short* __restrict__ Opart, const float* __restrict__ Ml,
    float* __restrict__ out) {
  int g = blockIdx.x * 256 + threadIdx.x;   // 131072 total
  int d8 = (g & 7) * 8;
  int row = g >> 3;               // 0..16383
  int b = row >> 12;
  int t = row & (T_SEQ - 1);
  int qp = t >> 8;
  int r256 = t & 255;
  int nch = qp + 1;
  int us = 0;
  for (int q = 15; q > qp; --q) us += q + 1;
  float M = -1e30f;
  for (int cc = 0; cc < nch; ++cc) {
    int part = (us + cc) * 4 + b;
    M = fmaxf(M, Ml[(size_t)part * 512 + r256 * 2]);
  }
  float L = 0.f;
  float o[8];
  #pragma unroll
  for (int j = 0; j < 8; ++j) o[j] = 0.f;
  for (int cc = 0; cc < nch; ++cc) {
    int part = (us + cc) * 4 + b;
    float mc = Ml[(size_t)part * 512 + r256 * 2];
    float lc = Ml[(size_t)part * 512 + r256 * 2 + 1];
    float w = exp2fast(mc - M) * lc;
    L += w;
    uint4 v = *(const uint4*)&Opart[(size_t)part * 16384 + r256 * 64 + d8];
    const unsigned short* pv = (const unsigned short*)&v;
    #pragma unroll
    for (int j = 0; j < 8; ++j) o[j] += w * bf2f(pv[j]);
  }
  float inv = 1.0f / L;
  size_t og = ((size_t)b * T_SEQ + qp * 256 + r256) * 64 + d8;
  float4 r0 = make_float4(o[0] * inv, o[1] * inv, o[2] * inv, o[3] * inv);
  float4 r1 = make_float4(o[4] * inv, o[5] * inv, o[6] * inv, o[7] * inv);
  *(float4*)&out[og] = r0;
  *(float4*)&out[og + 4] = r1;
}

extern "C" void kernel_launch(void* const* d_in, const int* in_sizes, int n_in,
                              void* d_out, int out_size, void* d_ws, size_t ws_size,
                              hipStream_t stream) {
  const float* x  = (const float*)d_in[0];
  const float* Wk = (const float*)d_in[1];
  const float* Wv = (const float*)d_in[2];
  unsigned short* Kb = (unsigned short*)d_ws;                 // 2 MB
  unsigned short* Vb = Kb + (size_t)NROWS * HD;               // 2 MB
  unsigned short* Wt = Vb + (size_t)NROWS * HD;               // 256 KB
  unsigned short* Opart = Wt + (size_t)128 * CDIM;            // 544 * 16384 * 2B = 17.8 MB
  float* Ml = (float*)(Opart + (size_t)544 * 16384);          // 544 * 512 * 4B = 1.1 MB
  float* o = (float*)d_out;

  prep_w<<<128, 256, 0, stream>>>(Wk, Wv, Wt);
  proj_mfma<<<256, 256, 0, stream>>>(x, Wt, Kb, Vb);
  attn_part<<<544, 256, 0, stream>>>(Kb, Vb, Opart, Ml);
  attn_merge<<<512, 256, 0, stream>>>(Opart, Ml, o);
}

// Round 18
// 101.478 us; speedup vs baseline: 1.0134x; 1.0134x over previous
//
#include <hip/hip_runtime.h>

typedef short bf16x8 __attribute__((ext_vector_type(8)));
typedef float f32x4 __attribute__((ext_vector_type(4)));
typedef float f32x16 __attribute__((ext_vector_type(16)));
typedef unsigned u32x4v __attribute__((ext_vector_type(4)));

#define T_SEQ 4096
#define CDIM  1024
#define HD    64
#define NROWS 16384  // B*T

__device__ inline float exp2fast(float x) {
  return __builtin_amdgcn_exp2f(x);   // v_exp_f32: D = 2^S0
}

__device__ inline unsigned short f2bf(float f) {
  unsigned u = __builtin_bit_cast(unsigned, f);
  u = (u + 0x7fffu + ((u >> 16) & 1u)) >> 16;
  return (unsigned short)u;
}
__device__ inline unsigned cvt_pk_bf16(float lo, float hi) {
  unsigned r;
  asm("v_cvt_pk_bf16_f32 %0, %1, %2" : "=v"(r) : "v"(lo), "v"(hi));
  return r;
}
__device__ inline float bf2f(unsigned short u) {
  unsigned v = (unsigned)u << 16;
  return __builtin_bit_cast(float, v);
}

// ---------------- W prep: Wt[n][k] bf16, n<64 = Wk col n, n>=64 = Wv col ----------------
__global__ __launch_bounds__(256) void prep_w(
    const float* __restrict__ Wk, const float* __restrict__ Wv,
    unsigned short* __restrict__ Wt) {
  int n = blockIdx.x;
  const float* W = (n < 64) ? Wk : Wv;
  int col = n & 63;
  for (int k = threadIdx.x; k < CDIM; k += 256)
    Wt[(size_t)n * CDIM + k] = f2bf(W[(size_t)k * HD + col]);
}

// ---------------- projection GEMM: [K|V] = x @ Wt^T, bf16 MFMA ----------------
// Tile M=32, N=128, BK=128. grid 512 -> 2 blocks/CU (2 waves/SIMD). 8 kk-iters.
// 4 waves = wm(2, 16-row frag) x wn(2, K|V). T14: next loads issued after barrier.
__global__ __launch_bounds__(256) void proj_mfma(
    const float* __restrict__ x, const unsigned short* __restrict__ Wt,
    unsigned short* __restrict__ Kb, unsigned short* __restrict__ Vb) {
  __shared__ __align__(16) unsigned char xsb[8192];   // x tile bf16 [32][128], swizzled, 256B rows
  __shared__ __align__(16) unsigned char wsb[32768];  // W tile bf16 [128][128], swizzled, 256B rows
  const int tid = threadIdx.x;
  const int lane = tid & 63, wave = tid >> 6;
  const int wm = wave & 1, wn = wave >> 1;
  const int lg = lane >> 4, lc = lane & 15;
  const int row0 = blockIdx.x * 32;

  float4 xreg[4];
  uint4 wreg[8];
  auto load_tiles = [&](int kk) {
    #pragma unroll
    for (int p = 0; p < 4; ++p) {
      int idx = tid + 256 * p, r = idx >> 5, c4 = idx & 31;
      xreg[p] = *(const float4*)&x[(size_t)(row0 + r) * CDIM + kk + c4 * 4];
    }
    #pragma unroll
    for (int p = 0; p < 8; ++p) {
      int idx = tid + 256 * p, r = idx >> 4, c8 = idx & 15;
      wreg[p] = *(const uint4*)&Wt[(size_t)r * CDIM + kk + c8 * 8];
    }
  };
  auto write_tiles = [&]() {
    #pragma unroll
    for (int p = 0; p < 4; ++p) {
      int idx = tid + 256 * p, r = idx >> 5, c4 = idx & 31;
      uint2 v;
      v.x = cvt_pk_bf16(xreg[p].x, xreg[p].y);
      v.y = cvt_pk_bf16(xreg[p].z, xreg[p].w);
      int byt = (r * 256 + c4 * 8) ^ ((r & 7) << 4);
      *(uint2*)(xsb + byt) = v;
    }
    #pragma unroll
    for (int p = 0; p < 8; ++p) {
      int idx = tid + 256 * p, r = idx >> 4, c8 = idx & 15;
      int byt = (r * 256 + c8 * 16) ^ ((r & 7) << 4);
      *(uint4*)(wsb + byt) = wreg[p];
    }
  };

  f32x4 acc[4];
  #pragma unroll
  for (int nf = 0; nf < 4; ++nf) acc[nf] = (f32x4){0.f, 0.f, 0.f, 0.f};

  load_tiles(0);
  for (int kk = 0; kk < CDIM; kk += 128) {
    __syncthreads();
    write_tiles();              // vmcnt wait for regs loaded during prev compute
    __syncthreads();
    if (kk + 128 < CDIM) load_tiles(kk + 128);  // in flight during MFMA phase
    #pragma unroll
    for (int dd = 0; dd < 4; ++dd) {
      bf16x8 a, bfr[4];
      {
        int r = wm * 16 + lc;
        int sw = (r & 7) << 4;
        a = *(const bf16x8*)(xsb + ((r * 256 + dd * 64 + lg * 16) ^ sw));  // 64B per 32-elem k-chunk
      }
      #pragma unroll
      for (int nf = 0; nf < 4; ++nf) {
        int r = wn * 64 + nf * 16 + lc;
        int sw = (r & 7) << 4;
        bfr[nf] = *(const bf16x8*)(wsb + ((r * 256 + dd * 64 + lg * 16) ^ sw));
      }
      __builtin_amdgcn_s_setprio(1);
      #pragma unroll
      for (int nf = 0; nf < 4; ++nf)
        acc[nf] = __builtin_amdgcn_mfma_f32_16x16x32_bf16(a, bfr[nf], acc[nf], 0, 0, 0);
      __builtin_amdgcn_s_setprio(0);
    }
  }

  unsigned short* Ob = (wn == 0) ? Kb : Vb;
  #pragma unroll
  for (int r = 0; r < 4; ++r) {
    int rg = row0 + wm * 16 + lg * 4 + r;
    #pragma unroll
    for (int nf = 0; nf < 4; ++nf)
      Ob[(size_t)rg * HD + nf * 16 + lc] = f2bf(acc[nf][r]);
  }
}

// ---------------- split-K flash attention, swapped QK^T, 32x32 MFMA ----------------
// (byte-identical to round 16 — verified 48.5 us) K+V in LDS, pair-fused subtiles,
// joint softmax over 32 scores, 1088 blocks, chunk = 256 keys.
__global__ __launch_bounds__(256) void attn_part(
    const unsigned short* __restrict__ Kb, const unsigned short* __restrict__ Vb,
    unsigned short* __restrict__ Opart, float* __restrict__ Ml) {
  __shared__ __align__(16) unsigned char lds[32768];  // 2 bufs x (K 8KB + V^T 8KB)

  const int tid = threadIdx.x;
  const int lane = tid & 63;
  const int wq = tid >> 6;
  const int hi = lane >> 5;
  const int lq = lane & 31;

  const int b = blockIdx.x & 3;
  int qb = 0, c = 0;
  {
    int u = blockIdx.x >> 2, acc = 0;
    for (int q = 31; q >= 0; --q) {      // heavy (qb=31) chunks first
      int nch = (q + 2) >> 1;            // ceil((q+1)*128 / 256)
      if (u < acc + nch) { qb = q; c = u - acc; break; }
      acc += nch;
    }
  }
  const int kstart = c * 256;
  const int kend = min(kstart + 256, (qb + 1) * 128);
  const int nit = (kend - kstart) >> 6;  // 2 or 4
  const int q0g = qb * 128 + wq * 32;
  const int qg = q0g + lq;
  const size_t base = (size_t)b * T_SEQ;
  const float SCALE2 = 0.18033688011112042f;     // 0.125 * log2(e)

  // Q B-fragments (Q == K rows), pre-scaled by SCALE2
  bf16x8 qf[4];
  {
    const unsigned short* qp = &Kb[(base + q0g + lq) * HD];
    #pragma unroll
    for (int dd = 0; dd < 4; ++dd) {
      bf16x8 t = *(const bf16x8*)&qp[dd * 16 + hi * 8];
      const unsigned short* ts = (const unsigned short*)&t;
      unsigned ow[4];
      #pragma unroll
      for (int w = 0; w < 4; ++w)
        ow[w] = cvt_pk_bf16(bf2f(ts[2 * w]) * SCALE2, bf2f(ts[2 * w + 1]) * SCALE2);
      u32x4v ov = {ow[0], ow[1], ow[2], ow[3]};
      qf[dd] = __builtin_bit_cast(bf16x8, ov);
    }
  }

  f32x16 oT0, oT1;
  #pragma unroll
  for (int r = 0; r < 16; ++r) { oT0[r] = 0.f; oT1[r] = 0.f; }
  float mreg = -1e30f, lreg = 0.f;               // m in log2 domain

  uint4 kreg[2], vreg0, vreg1;
  auto load_kv = [&](int jj) {
    const size_t kv0 = (base + kstart + (size_t)jj * 64) * HD;
    #pragma unroll
    for (int p = 0; p < 2; ++p) {
      int idx = tid + 256 * p, r = idx >> 3, c8 = idx & 7;
      kreg[p] = *(const uint4*)&Kb[kv0 + (size_t)r * HD + c8 * 8];
    }
    int key0 = (tid & 31) * 2, d0 = (tid >> 5) * 8;
    vreg0 = *(const uint4*)&Vb[kv0 + (size_t)key0 * HD + d0];
    vreg1 = *(const uint4*)&Vb[kv0 + (size_t)(key0 + 1) * HD + d0];
  };
  auto write_kv = [&](int buf) {
    unsigned char* kb = lds + buf * 16384;
    unsigned char* vb = kb + 8192;
    #pragma unroll
    for (int p = 0; p < 2; ++p) {
      int idx = tid + 256 * p, r = idx >> 3, c8 = idx & 7;
      int byt = (r * 128 + c8 * 16) ^ ((r & 7) << 4);
      *(uint4*)(kb + byt) = kreg[p];
    }
    int key0 = (tid & 31) * 2, d0 = (tid >> 5) * 8;
    const unsigned short* pa = (const unsigned short*)&vreg0;
    const unsigned short* pb = (const unsigned short*)&vreg1;
    #pragma unroll
    for (int j = 0; j < 8; ++j) {
      unsigned val = (unsigned)pa[j] | ((unsigned)pb[j] << 16);
      int d = d0 + j;
      int byt = (d * 128 + key0 * 2) ^ ((d & 7) << 4);
      *(unsigned*)(vb + byt) = val;
    }
  };

  auto qk = [&](int buf, int ksub) -> f32x16 {
    const unsigned char* kb = lds + buf * 16384;
    f32x16 sacc;
    #pragma unroll
    for (int r = 0; r < 16; ++r) sacc[r] = 0.f;
    const int krow = ksub * 32 + lq;
    const int ksw = (krow & 7) << 4;
    #pragma unroll
    for (int dd = 0; dd < 4; ++dd) {
      bf16x8 kf = *(const bf16x8*)(kb + ((krow * 128 + dd * 32 + hi * 16) ^ ksw));
      sacc = __builtin_amdgcn_mfma_f32_32x32x16_bf16(kf, qf[dd], sacc, 0, 0, 0);
    }
    return sacc;
  };
  auto maskdiag = [&](f32x16& s, int kbase_s) {
    #pragma unroll
    for (int r = 0; r < 16; ++r) {
      int key = kbase_s + (r & 3) + 8 * (r >> 2) + 4 * hi;
      if (key > qg) s[r] = -1e38f;
    }
  };
  auto max16 = [&](const f32x16& s) -> float {
    return fmaxf(
        fmaxf(fmaxf(fmaxf(s[0], s[1]), fmaxf(s[2], s[3])),
              fmaxf(fmaxf(s[4], s[5]), fmaxf(s[6], s[7]))),
        fmaxf(fmaxf(fmaxf(s[8], s[9]), fmaxf(s[10], s[11])),
              fmaxf(fmaxf(s[12], s[13]), fmaxf(s[14], s[15]))));
  };
  auto pack2 = [&](const f32x16& s, bf16x8& p1, bf16x8& p2) {
    unsigned pk[8];
    #pragma unroll
    for (int i = 0; i < 8; ++i) pk[i] = cvt_pk_bf16(s[2 * i], s[2 * i + 1]);
    unsigned wA[4], wB[4];
    #pragma unroll
    for (int i = 0; i < 2; ++i) {
      unsigned a0 = pk[i], b0 = pk[2 + i];
      unsigned sa = (unsigned)__shfl_xor((int)a0, 32);
      unsigned sb = (unsigned)__shfl_xor((int)b0, 32);
      wA[i] = hi ? sb : a0;
      wA[2 + i] = hi ? b0 : sa;
      unsigned c0 = pk[4 + i], d0v = pk[6 + i];
      unsigned sc = (unsigned)__shfl_xor((int)c0, 32);
      unsigned sd = (unsigned)__shfl_xor((int)d0v, 32);
      wB[i] = hi ? sd : c0;
      wB[2 + i] = hi ? d0v : sc;
    }
    u32x4v t1v = {wA[0], wA[1], wA[2], wA[3]};
    u32x4v t2v = {wB[0], wB[1], wB[2], wB[3]};
    p1 = __builtin_bit_cast(bf16x8, t1v);
    p2 = __builtin_bit_cast(bf16x8, t2v);
  };
  auto pv = [&](int buf, int ksub, bf16x8 pb1, bf16x8 pb2) {
    const unsigned char* vb = lds + buf * 16384 + 8192;
    const int cb = ksub * 64;
    {
      int drow = lq;
      int swz = (drow & 7) << 4;
      bf16x8 v0 = *(const bf16x8*)(vb + ((drow * 128 + cb + hi * 16) ^ swz));
      bf16x8 v1 = *(const bf16x8*)(vb + ((drow * 128 + cb + 32 + hi * 16) ^ swz));
      oT0 = __builtin_amdgcn_mfma_f32_32x32x16_bf16(v0, pb1, oT0, 0, 0, 0);
      oT0 = __builtin_amdgcn_mfma_f32_32x32x16_bf16(v1, pb2, oT0, 0, 0, 0);
    }
    {
      int drow = 32 + lq;
      int swz = (drow & 7) << 4;
      bf16x8 v0 = *(const bf16x8*)(vb + ((drow * 128 + cb + hi * 16) ^ swz));
      bf16x8 v1 = *(const bf16x8*)(vb + ((drow * 128 + cb + 32 + hi * 16) ^ swz));
      oT1 = __builtin_amdgcn_mfma_f32_32x32x16_bf16(v0, pb1, oT1, 0, 0, 0);
      oT1 = __builtin_amdgcn_mfma_f32_32x32x16_bf16(v1, pb2, oT1, 0, 0, 0);
    }
  };

  load_kv(0);
  write_kv(0);
  for (int jj = 0; jj < nit; ++jj) {
    const int cur = jj & 1;
    __syncthreads();                     // buf[cur] staged
    if (jj + 1 < nit) load_kv(jj + 1);   // in flight during compute
    const int kb0 = kstart + jj * 64;

    if (kb0 + 32 <= q0g) {
      // ---- pair path: both subtiles, joint softmax ----
      __builtin_amdgcn_s_setprio(1);
      f32x16 s0 = qk(cur, 0);
      f32x16 s1 = qk(cur, 1);
      __builtin_amdgcn_s_setprio(0);
      if (kb0 + 32 == q0g) maskdiag(s1, kb0 + 32);
      float mx = fmaxf(max16(s0), max16(s1));
      mx = fmaxf(mx, __shfl_xor(mx, 32));
      if (!__all(mx <= mreg + 11.5f)) {
        float mn = fmaxf(mreg, mx);
        float al = exp2fast(mreg - mn);
        lreg *= al;
        #pragma unroll
        for (int r = 0; r < 16; ++r) { oT0[r] *= al; oT1[r] *= al; }
        mreg = mn;
      }
      float ps = 0.f;
      #pragma unroll
      for (int r = 0; r < 16; ++r) {
        float p0 = exp2fast(s0[r] - mreg);
        float p1 = exp2fast(s1[r] - mreg);
        ps += p0 + p1;
        s0[r] = p0;
        s1[r] = p1;
      }
      lreg += ps + __shfl_xor(ps, 32);
      bf16x8 pa1, pa2, pbb1, pbb2;
      pack2(s0, pa1, pa2);
      pack2(s1, pbb1, pbb2);
      __builtin_amdgcn_s_setprio(1);
      pv(cur, 0, pa1, pa2);
      pv(cur, 1, pbb1, pbb2);
      __builtin_amdgcn_s_setprio(0);
    } else if (kb0 <= q0g) {
      // ---- single path: sub0 only (possibly diagonal) ----
      __builtin_amdgcn_s_setprio(1);
      f32x16 s0 = qk(cur, 0);
      __builtin_amdgcn_s_setprio(0);
      if (kb0 == q0g) maskdiag(s0, kb0);
      float mx = max16(s0);
      mx = fmaxf(mx, __shfl_xor(mx, 32));
      if (!__all(mx <= mreg + 11.5f)) {
        float mn = fmaxf(mreg, mx);
        float al = exp2fast(mreg - mn);
        lreg *= al;
        #pragma unroll
        for (int r = 0; r < 16; ++r) { oT0[r] *= al; oT1[r] *= al; }
        mreg = mn;
      }
      float ps = 0.f;
      #pragma unroll
      for (int r = 0; r < 16; ++r) {
        float p = exp2fast(s0[r] - mreg);
        ps += p;
        s0[r] = p;
      }
      lreg += ps + __shfl_xor(ps, 32);
      bf16x8 pa1, pa2;
      pack2(s0, pa1, pa2);
      __builtin_amdgcn_s_setprio(1);
      pv(cur, 0, pa1, pa2);
      __builtin_amdgcn_s_setprio(0);
    }

    if (jj + 1 < nit) write_kv(cur ^ 1); // vmcnt wait lands post-compute
  }

  // ---- write normalized bf16 partial [128 q][64 d] + (m2, l) ----
  unsigned short* op = Opart + (size_t)blockIdx.x * 8192;
  const float invl = 1.0f / lreg;
  const int qrow = wq * 32 + lq;
  #pragma unroll
  for (int g = 0; g < 4; ++g) {
    int d0 = 8 * g + 4 * hi;
    uint2 w0, w1;
    w0.x = cvt_pk_bf16(oT0[4 * g] * invl, oT0[4 * g + 1] * invl);
    w0.y = cvt_pk_bf16(oT0[4 * g + 2] * invl, oT0[4 * g + 3] * invl);
    w1.x = cvt_pk_bf16(oT1[4 * g] * invl, oT1[4 * g + 1] * invl);
    w1.y = cvt_pk_bf16(oT1[4 * g + 2] * invl, oT1[4 * g + 3] * invl);
    *(uint2*)&op[qrow * 64 + d0] = w0;
    *(uint2*)&op[qrow * 64 + d0 + 32] = w1;
  }
  if (hi == 0) {
    Ml[(size_t)blockIdx.x * 256 + qrow * 2] = mreg;
    Ml[(size_t)blockIdx.x * 256 + qrow * 2 + 1] = lreg;
  }
}

// ---------------- phase 2: merge chunk partials (8 d per thread, uint4 loads) ----------------
__global__ __launch_bounds__(256) void attn_merge(
    const unsigned short* __restrict__ Opart, const float* __restrict__ Ml,
    float* __restrict__ out) {
  int g = blockIdx.x * 256 + threadIdx.x;   // 131072 total
  int d8 = (g & 7) * 8;
  int q128 = (g >> 3) & 127;
  int qb = (g >> 10) & 31;
  int b = (g >> 15) & 3;
  int nch = (qb + 2) >> 1;
  int us = 0;
  for (int q = 31; q > qb; --q) us += (q + 2) >> 1;
  float M = -1e30f;
  for (int cc = 0; cc < nch; ++cc) {
    int part = (us + cc) * 4 + b;
    M = fmaxf(M, Ml[(size_t)part * 256 + q128 * 2]);
  }
  float L = 0.f;
  float o[8];
  #pragma unroll
  for (int j = 0; j < 8; ++j) o[j] = 0.f;
  for (int cc = 0; cc < nch; ++cc) {
    int part = (us + cc) * 4 + b;
    float mc = Ml[(size_t)part * 256 + q128 * 2];
    float lc = Ml[(size_t)part * 256 + q128 * 2 + 1];
    float w = exp2fast(mc - M) * lc;
    L += w;
    uint4 v = *(const uint4*)&Opart[(size_t)part * 8192 + q128 * 64 + d8];
    const unsigned short* pv = (const unsigned short*)&v;
    #pragma unroll
    for (int j = 0; j < 8; ++j) o[j] += w * bf2f(pv[j]);
  }
  float inv = 1.0f / L;
  size_t og = ((size_t)b * T_SEQ + qb * 128 + q128) * 64 + d8;
  float4 r0 = make_float4(o[0] * inv, o[1] * inv, o[2] * inv, o[3] * inv);
  float4 r1 = make_float4(o[4] * inv, o[5] * inv, o[6] * inv, o[7] * inv);
  *(float4*)&out[og] = r0;
  *(float4*)&out[og + 4] = r1;
}

extern "C" void kernel_launch(void* const* d_in, const int* in_sizes, int n_in,
                              void* d_out, int out_size, void* d_ws, size_t ws_size,
                              hipStream_t stream) {
  const float* x  = (const float*)d_in[0];
  const float* Wk = (const float*)d_in[1];
  const float* Wv = (const float*)d_in[2];
  unsigned short* Kb = (unsigned short*)d_ws;                 // 2 MB
  unsigned short* Vb = Kb + (size_t)NROWS * HD;               // 2 MB
  unsigned short* Wt = Vb + (size_t)NROWS * HD;               // 256 KB
  unsigned short* Opart = Wt + (size_t)128 * CDIM;            // 1088 * 8192 * 2B = 17.8 MB
  float* Ml = (float*)(Opart + (size_t)1088 * 8192);          // 1088 * 256 * 4B = 1.1 MB
  float* o = (float*)d_out;

  prep_w<<<128, 256, 0, stream>>>(Wk, Wv, Wt);
  proj_mfma<<<512, 256, 0, stream>>>(x, Wt, Kb, Vb);
  attn_part<<<1088, 256, 0, stream>>>(Kb, Vb, Opart, Ml);
  attn_merge<<<512, 256, 0, stream>>>(Opart, Ml, o);
}